// Round 5
// baseline (988.523 us; speedup 1.0000x reference)
//
#include <hip/hip_runtime.h>
#include <stdint.h>

// ---------------------------------------------------------------------------
// UpBlock: 5 chained sparse convs (gather-GEMM), bf16 MFMA.
// out[i] = sum_k feats[nbr[k,i]] @ W[k]; BN+LeakyReLU epilogues; skip add L2.
//
// v6: v5's 32-row reg-staged gather-to-LDS with the spill actually fixed.
// v4/v5 both spilled the staging regs to scratch (WRITE_SIZE == staged bytes;
// v5 VGPR_Count=64 shows regalloc squeezed the budget). Two fixes:
//   1. __launch_bounds__(64, 2): explicit 256-VGPR budget (true pressure ~110).
//   2. Staging regs are UNCONDITIONALLY defined: last tap peeled out of the
//      loop, idx prefetch clamped -- no conditional defs crossing the back
//      edge (the pattern that demotes arrays to scratch).
// Per tap: 32 rows gathered with full-row-covering dwordx4 loads (1
// transaction per 128B line vs 4x for per-lane fragment gathers), ds_write'd
// into a single 8KB LDS tile (XOR chunk-swizzle), read back as MFMA
// fragments. Next tap's gathers issue before the current tap's compute.
//
// mfma_f32_32x32x16_bf16:
//   A[m=lane&31][k=(lane>>5)*8+j], B[k=(lane>>5)*8+j][n=lane&31]
//   C/D: col=lane&31, row=(reg&3)+8*(reg>>2)+4*(lane>>5)
// ---------------------------------------------------------------------------

typedef __bf16 bf16x8 __attribute__((ext_vector_type(8)));
typedef float f32x16 __attribute__((ext_vector_type(16)));

__device__ __forceinline__ uint16_t f2bf(float f) {
    uint32_t u = __builtin_bit_cast(uint32_t, f);
    u = (u + 0x7fffu + ((u >> 16) & 1u)) >> 16;   // round-to-nearest-even
    return (uint16_t)u;
}

__device__ __forceinline__ bf16x8 ldb8(const uint16_t* p) {
    return __builtin_bit_cast(bf16x8, *reinterpret_cast<const uint4*>(p));
}

// --- convert x_feats (f32) -> bf16, 8 elems/thread --------------------------
__global__ void convert_x(const float* __restrict__ in, uint16_t* __restrict__ out, int n8) {
    int t = blockIdx.x * blockDim.x + threadIdx.x;
    if (t >= n8) return;
    const float4* p = reinterpret_cast<const float4*>(in) + 2 * (size_t)t;
    float4 f0 = p[0], f1 = p[1];
    uint32_t w0 = (uint32_t)f2bf(f0.x) | ((uint32_t)f2bf(f0.y) << 16);
    uint32_t w1 = (uint32_t)f2bf(f0.z) | ((uint32_t)f2bf(f0.w) << 16);
    uint32_t w2 = (uint32_t)f2bf(f1.x) | ((uint32_t)f2bf(f1.y) << 16);
    uint32_t w3 = (uint32_t)f2bf(f1.z) | ((uint32_t)f2bf(f1.w) << 16);
    uint4 v; v.x = w0; v.y = w1; v.z = w2; v.w = w3;
    *reinterpret_cast<uint4*>(out + 8 * (size_t)t) = v;
}

// --- pack weights into MFMA B-fragment order + BN scale/shift ---------------
// dst element [(((k*S + s)*2 + nt)*64 + lane)*8 + j] = bf16(W[k][ci][c])
//   ci = s*16 + (lane>>5)*8 + j,  c = nt*32 + (lane&31),  S = CIN/16
__global__ void pack_weights(const float* __restrict__ w1, const float* __restrict__ wt,
                             const float* __restrict__ w2, const float* __restrict__ w3,
                             const float* __restrict__ w4, const float* __restrict__ bn,
                             uint16_t* __restrict__ p1, uint16_t* __restrict__ pt,
                             uint16_t* __restrict__ p2, uint16_t* __restrict__ p3,
                             uint16_t* __restrict__ p4, float* __restrict__ bnps) {
    int w = blockIdx.y;
    int t = blockIdx.x * blockDim.x + threadIdx.x;
    if (w == 5) {  // BN scale/shift precompute
        if (t < 256) {
            int l = t >> 6, c = t & 63;
            float g = bn[(l * 4 + 0) * 64 + c];
            float b = bn[(l * 4 + 1) * 64 + c];
            float m = bn[(l * 4 + 2) * 64 + c];
            float v = bn[(l * 4 + 3) * 64 + c];
            float sc = g * rsqrtf(v + 1e-5f);
            bnps[(l * 2 + 0) * 64 + c] = sc;
            bnps[(l * 2 + 1) * 64 + c] = b - m * sc;
        }
        return;
    }
    const float* src; uint16_t* dst; int K, CIN;
    switch (w) {
        case 0:  src = w1; dst = p1; K = 27; CIN = 128; break;
        case 1:  src = wt; dst = pt; K = 27; CIN = 64;  break;
        case 2:  src = w2; dst = p2; K = 9;  CIN = 64;  break;
        case 3:  src = w3; dst = p3; K = 9;  CIN = 64;  break;
        default: src = w4; dst = p4; K = 27; CIN = 64;  break;
    }
    int S = CIN / 16;
    int F = K * S * 2 * 64;
    if (t >= F) return;
    int lane = t & 63;
    int r = t >> 6;
    int nt = r & 1; r >>= 1;
    int s = r % S;
    int k = r / S;
    int c = nt * 32 + (lane & 31);
    int cib = s * 16 + (lane >> 5) * 8;
    #pragma unroll
    for (int j = 0; j < 8; ++j)
        dst[(size_t)t * 8 + j] = f2bf(src[((size_t)k * CIN + cib + j) * 64 + c]);
}

// --- one sparse-conv layer ---------------------------------------------------
// 1 wave per wg, 32 output rows. Per tap: rows gathered to registers with
// full-row-covering dwordx4 loads, ds_write'd into a single LDS tile (XOR
// chunk-swizzle), fragments read back with the matching swizzle. Next tap's
// gathers overlap current tap's MFMAs (unconditional defs, peeled last tap).
// MODE 0: BN+LeakyReLU -> bf16   MODE 1: +skip -> bf16   MODE 2: BN+LeakyReLU -> f32
template <int CIN, int K, int MODE>
__global__ __launch_bounds__(64, 2)
void conv_layer(const uint16_t* __restrict__ feats,  // [N][CIN] bf16
                const uint16_t* __restrict__ wf,     // packed [K][CIN/16][2][64][8] bf16
                const int* __restrict__ nbr,         // [K][N]
                const int npts,
                const float* __restrict__ bnp,       // [2][64] scale/shift (or null)
                const float* __restrict__ skip,      // [N][64] f32 (or null)
                uint16_t* __restrict__ outb,
                float* __restrict__ outf) {
    constexpr int S    = CIN / 16;   // MFMA K-steps per tap
    constexpr int CPR  = CIN / 8;    // 16B chunks per row (16 or 8)
    constexpr int RPI  = 64 / CPR;   // complete rows covered per load instr
    constexpr int NSTG = 32 / RPI;   // load/write instrs per tap (8 or 4)
    __shared__ uint4 sm4[32 * CPR];  // single-buffer 32-row tile (8KB / 4KB)

    const int lane = threadIdx.x;
    const int l31  = lane & 31;
    const int hi   = lane >> 5;          // which K-half of the fragment
    const int xr   = l31 & 7;            // read-side swizzle key
    const int base = blockIdx.x * 32;
    const int g    = min(base + l31, npts - 1);   // lane's output row

    // staging lane roles: lane covers chunk t of rows (it*RPI + sub)
    const int sub = lane >> ((CPR == 16) ? 4 : 3);
    const int t   = lane & (CPR - 1);

    const uint16_t* sm = (const uint16_t*)sm4;

    f32x16 acc0 = {0,0,0,0,0,0,0,0,0,0,0,0,0,0,0,0};
    f32x16 acc1 = {0,0,0,0,0,0,0,0,0,0,0,0,0,0,0,0};

    uint4 st[NSTG];

    auto gather = [&](int idxreg) {
        #pragma unroll
        for (int it = 0; it < NSTG; ++it) {
            const int row = it * RPI + sub;
            const int src = __shfl(idxreg, row);
            st[it] = *reinterpret_cast<const uint4*>(feats + (size_t)src * CIN + t * 8);
        }
    };
    auto lds_write = [&]() {
        #pragma unroll
        for (int it = 0; it < NSTG; ++it) {
            const int row = it * RPI + sub;
            sm4[row * CPR + (t ^ (row & 7))] = st[it];
        }
    };
    auto compute = [&](int k) {
        const uint16_t* bp = wf + (size_t)k * (S * 1024) + lane * 8;
        #pragma unroll
        for (int s = 0; s < S; ++s) {
            const int sl = (2 * s + hi) ^ xr;      // swizzled chunk slot
            bf16x8 a0 = ldb8(sm + (size_t)l31 * CIN + sl * 8);
            bf16x8 b0 = ldb8(bp + s * 1024);
            bf16x8 b1 = ldb8(bp + s * 1024 + 512);
            acc0 = __builtin_amdgcn_mfma_f32_32x32x16_bf16(a0, b0, acc0, 0, 0, 0);
            acc1 = __builtin_amdgcn_mfma_f32_32x32x16_bf16(a0, b1, acc1, 0, 0, 0);
        }
    };

    // prologue: gather tap 0; idxn = index for tap 1 (K >= 2 always here)
    gather(nbr[g]);
    int idxn = nbr[(size_t)npts + g];

    // main loop computes taps 0..K-2; gather of tap kk+1 is UNCONDITIONAL
    for (int kk = 0; kk < K - 1; ++kk) {
        lds_write();                 // tap kk -> LDS (in-order vs last reads)
        gather(idxn);                // tap kk+1 -> regs (overlaps MFMAs below)
        idxn = nbr[(size_t)min(kk + 2, K - 1) * npts + g];   // clamped
        compute(kk);
    }
    // peeled last tap
    lds_write();
    compute(K - 1);

    // ---- epilogue: straight from accumulators (validated layout) -----------
    const int c0 = l31, c1 = 32 + l31;
    float sc0 = 0.f, sh0 = 0.f, sc1 = 0.f, sh1 = 0.f;
    if (MODE != 1) {
        sc0 = bnp[c0]; sh0 = bnp[64 + c0];
        sc1 = bnp[c1]; sh1 = bnp[64 + c1];
    }
    #pragma unroll
    for (int reg = 0; reg < 16; ++reg) {
        const int row = (reg & 3) + 8 * (reg >> 2) + 4 * hi;   // 0..31
        const int gr = base + row;
        float v0 = acc0[reg], v1 = acc1[reg];
        if (MODE != 1) {
            v0 = v0 * sc0 + sh0; v0 = v0 >= 0.f ? v0 : 0.01f * v0;
            v1 = v1 * sc1 + sh1; v1 = v1 >= 0.f ? v1 : 0.01f * v1;
        }
        if (gr < npts) {
            if (MODE == 1) { v0 += skip[(size_t)gr * 64 + c0]; v1 += skip[(size_t)gr * 64 + c1]; }
            if (MODE == 2) {
                outf[(size_t)gr * 64 + c0] = v0; outf[(size_t)gr * 64 + c1] = v1;
            } else {
                outb[(size_t)gr * 64 + c0] = f2bf(v0); outb[(size_t)gr * 64 + c1] = f2bf(v1);
            }
        }
    }
}

extern "C" void kernel_launch(void* const* d_in, const int* in_sizes, int n_in,
                              void* d_out, int out_size, void* d_ws, size_t ws_size,
                              hipStream_t stream) {
    const int N = in_sizes[0] / 128;
    const float* x    = (const float*)d_in[0];
    const float* skip = (const float*)d_in[1];
    const float* W1   = (const float*)d_in[2];
    const float* Wt   = (const float*)d_in[3];
    const float* W2   = (const float*)d_in[4];
    const float* W3   = (const float*)d_in[5];
    const float* W4   = (const float*)d_in[6];
    const float* bn   = (const float*)d_in[7];
    const int* nbr1   = (const int*)d_in[8];
    const int* nbrt   = (const int*)d_in[9];
    const int* nbr2   = (const int*)d_in[10];
    const int* nbr3   = (const int*)d_in[11];
    const int* nbr4   = (const int*)d_in[12];

    uint8_t* ws = (uint8_t*)d_ws;
    size_t off = 0;
    auto carve = [&](size_t bytes) -> void* {
        void* p = ws + off;
        off += (bytes + 255) & ~(size_t)255;
        return p;
    };
    uint16_t* xb  = (uint16_t*)carve((size_t)N * 128 * 2);
    uint16_t* hA  = (uint16_t*)carve((size_t)N * 64 * 2);
    uint16_t* hB  = (uint16_t*)carve((size_t)N * 64 * 2);
    uint16_t* p1  = (uint16_t*)carve((size_t)27 * 128 * 64 * 2);
    uint16_t* pt  = (uint16_t*)carve((size_t)27 * 64 * 64 * 2);
    uint16_t* p2  = (uint16_t*)carve((size_t)9 * 64 * 64 * 2);
    uint16_t* p3  = (uint16_t*)carve((size_t)9 * 64 * 64 * 2);
    uint16_t* p4  = (uint16_t*)carve((size_t)27 * 64 * 64 * 2);
    float*    bnp = (float*)carve((size_t)4 * 2 * 64 * 4);

    // prologue: convert + pack (re-done every call; ws is re-poisoned)
    const int n8 = N * 16;  // N*128/8
    convert_x<<<(n8 + 255) / 256, 256, 0, stream>>>(x, xb, n8);
    pack_weights<<<dim3(108, 6), 256, 0, stream>>>(W1, Wt, W2, W3, W4, bn,
                                                   p1, pt, p2, p3, p4, bnp);

    const int grid = (N + 31) / 32;   // 32 rows per 1-wave workgroup
    conv_layer<128, 27, 0><<<grid, 64, 0, stream>>>(xb, p1, nbr1, N, bnp + 0,   nullptr, hA, nullptr);
    conv_layer<64,  27, 1><<<grid, 64, 0, stream>>>(hA, pt, nbrt, N, nullptr,   skip,    hB, nullptr);
    conv_layer<64,   9, 0><<<grid, 64, 0, stream>>>(hB, p2, nbr2, N, bnp + 128, nullptr, hA, nullptr);
    conv_layer<64,   9, 0><<<grid, 64, 0, stream>>>(hA, p3, nbr3, N, bnp + 256, nullptr, hB, nullptr);
    conv_layer<64,  27, 2><<<grid, 64, 0, stream>>>(hB, p4, nbr4, N, bnp + 384, nullptr, nullptr, (float*)d_out);
}

// Round 6
// 459.958 us; speedup vs baseline: 2.1492x; 2.1492x over previous
//
#include <hip/hip_runtime.h>
#include <stdint.h>

// ---------------------------------------------------------------------------
// UpBlock: 5 chained sparse convs (gather-GEMM), bf16 MFMA.
// out[i] = sum_k feats[nbr[k,i]] @ W[k]; BN+LeakyReLU epilogues; skip add L2.
//
// v7: reg-staged gather-to-LDS with staging in NAMED registers (st0..st7).
// v4/v5/v6 all spilled the `uint4 st[NSTG]` staging ARRAY to scratch
// (WRITE_SIZE == staged bytes each time; v6 VGPR_Count=52 proves the array
// never lived in registers despite a 256-VGPR budget) -- aggregate + lambda
// capture defeats SROA. v7 uses individually named uint4 values with
// macro-expanded straight-line gather/write code: nothing to scalarize.
// Per tap: 32 rows gathered with full-row-covering dwordx4 loads (8 lines
// per instruction vs 32 for v1's scattered fragment gathers; every 128B line
// touched exactly once), ds_write'd into a single 8KB LDS tile (XOR
// chunk-swizzle), read back as MFMA fragments. Next tap's gathers issue
// before the current tap's compute; last tap peeled.
//
// mfma_f32_32x32x16_bf16:
//   A[m=lane&31][k=(lane>>5)*8+j], B[k=(lane>>5)*8+j][n=lane&31]
//   C/D: col=lane&31, row=(reg&3)+8*(reg>>2)+4*(lane>>5)
// ---------------------------------------------------------------------------

typedef __bf16 bf16x8 __attribute__((ext_vector_type(8)));
typedef float f32x16 __attribute__((ext_vector_type(16)));

__device__ __forceinline__ uint16_t f2bf(float f) {
    uint32_t u = __builtin_bit_cast(uint32_t, f);
    u = (u + 0x7fffu + ((u >> 16) & 1u)) >> 16;   // round-to-nearest-even
    return (uint16_t)u;
}

__device__ __forceinline__ bf16x8 ldb8(const uint16_t* p) {
    return __builtin_bit_cast(bf16x8, *reinterpret_cast<const uint4*>(p));
}

// --- convert x_feats (f32) -> bf16, 8 elems/thread --------------------------
__global__ void convert_x(const float* __restrict__ in, uint16_t* __restrict__ out, int n8) {
    int t = blockIdx.x * blockDim.x + threadIdx.x;
    if (t >= n8) return;
    const float4* p = reinterpret_cast<const float4*>(in) + 2 * (size_t)t;
    float4 f0 = p[0], f1 = p[1];
    uint32_t w0 = (uint32_t)f2bf(f0.x) | ((uint32_t)f2bf(f0.y) << 16);
    uint32_t w1 = (uint32_t)f2bf(f0.z) | ((uint32_t)f2bf(f0.w) << 16);
    uint32_t w2 = (uint32_t)f2bf(f1.x) | ((uint32_t)f2bf(f1.y) << 16);
    uint32_t w3 = (uint32_t)f2bf(f1.z) | ((uint32_t)f2bf(f1.w) << 16);
    uint4 v; v.x = w0; v.y = w1; v.z = w2; v.w = w3;
    *reinterpret_cast<uint4*>(out + 8 * (size_t)t) = v;
}

// --- pack weights into MFMA B-fragment order + BN scale/shift ---------------
// dst element [(((k*S + s)*2 + nt)*64 + lane)*8 + j] = bf16(W[k][ci][c])
//   ci = s*16 + (lane>>5)*8 + j,  c = nt*32 + (lane&31),  S = CIN/16
__global__ void pack_weights(const float* __restrict__ w1, const float* __restrict__ wt,
                             const float* __restrict__ w2, const float* __restrict__ w3,
                             const float* __restrict__ w4, const float* __restrict__ bn,
                             uint16_t* __restrict__ p1, uint16_t* __restrict__ pt,
                             uint16_t* __restrict__ p2, uint16_t* __restrict__ p3,
                             uint16_t* __restrict__ p4, float* __restrict__ bnps) {
    int w = blockIdx.y;
    int t = blockIdx.x * blockDim.x + threadIdx.x;
    if (w == 5) {  // BN scale/shift precompute
        if (t < 256) {
            int l = t >> 6, c = t & 63;
            float g = bn[(l * 4 + 0) * 64 + c];
            float b = bn[(l * 4 + 1) * 64 + c];
            float m = bn[(l * 4 + 2) * 64 + c];
            float v = bn[(l * 4 + 3) * 64 + c];
            float sc = g * rsqrtf(v + 1e-5f);
            bnps[(l * 2 + 0) * 64 + c] = sc;
            bnps[(l * 2 + 1) * 64 + c] = b - m * sc;
        }
        return;
    }
    const float* src; uint16_t* dst; int K, CIN;
    switch (w) {
        case 0:  src = w1; dst = p1; K = 27; CIN = 128; break;
        case 1:  src = wt; dst = pt; K = 27; CIN = 64;  break;
        case 2:  src = w2; dst = p2; K = 9;  CIN = 64;  break;
        case 3:  src = w3; dst = p3; K = 9;  CIN = 64;  break;
        default: src = w4; dst = p4; K = 27; CIN = 64;  break;
    }
    int S = CIN / 16;
    int F = K * S * 2 * 64;
    if (t >= F) return;
    int lane = t & 63;
    int r = t >> 6;
    int nt = r & 1; r >>= 1;
    int s = r % S;
    int k = r / S;
    int c = nt * 32 + (lane & 31);
    int cib = s * 16 + (lane >> 5) * 8;
    #pragma unroll
    for (int j = 0; j < 8; ++j)
        dst[(size_t)t * 8 + j] = f2bf(src[((size_t)k * CIN + cib + j) * 64 + c]);
}

// gather one staged chunk into a NAMED register (no arrays -> no scratch)
#define GATH(IT, DST)                                                          \
    do {                                                                       \
        const int row_ = (IT) * RPI + sub;                                     \
        const int src_ = __shfl(idxv, row_);                                   \
        DST = *reinterpret_cast<const uint4*>(feats + (size_t)src_ * CIN + t * 8); \
    } while (0)

// write one staged chunk to LDS at the XOR-swizzled slot
#define LWRT(IT, SRC)                                                          \
    do {                                                                       \
        const int row_ = (IT) * RPI + sub;                                     \
        sm4[row_ * CPR + (t ^ (row_ & 7))] = SRC;                              \
    } while (0)

#define GATH_ALL()                                                             \
    do {                                                                       \
        GATH(0, st0); GATH(1, st1); GATH(2, st2); GATH(3, st3);                \
        if constexpr (NSTG == 8) { GATH(4, st4); GATH(5, st5); GATH(6, st6); GATH(7, st7); } \
    } while (0)

#define LWRT_ALL()                                                             \
    do {                                                                       \
        LWRT(0, st0); LWRT(1, st1); LWRT(2, st2); LWRT(3, st3);                \
        if constexpr (NSTG == 8) { LWRT(4, st4); LWRT(5, st5); LWRT(6, st6); LWRT(7, st7); } \
    } while (0)

// --- one sparse-conv layer ---------------------------------------------------
// 1 wave per wg, 32 output rows. Per tap: rows gathered into named registers
// with full-row-covering dwordx4 loads, ds_write'd into a single LDS tile
// (XOR chunk-swizzle), fragments read back with the matching swizzle.
// Next tap's gathers overlap current tap's MFMAs.
// MODE 0: BN+LeakyReLU -> bf16   MODE 1: +skip -> bf16   MODE 2: BN+LeakyReLU -> f32
template <int CIN, int K, int MODE>
__global__ __launch_bounds__(64, 2)
void conv_layer(const uint16_t* __restrict__ feats,  // [N][CIN] bf16
                const uint16_t* __restrict__ wf,     // packed [K][CIN/16][2][64][8] bf16
                const int* __restrict__ nbr,         // [K][N]
                const int npts,
                const float* __restrict__ bnp,       // [2][64] scale/shift (or null)
                const float* __restrict__ skip,      // [N][64] f32 (or null)
                uint16_t* __restrict__ outb,
                float* __restrict__ outf) {
    constexpr int S    = CIN / 16;   // MFMA K-steps per tap
    constexpr int CPR  = CIN / 8;    // 16B chunks per row (16 or 8)
    constexpr int RPI  = 64 / CPR;   // complete rows covered per load instr
    constexpr int NSTG = 32 / RPI;   // load/write instrs per tap (8 or 4)
    __shared__ uint4 sm4[32 * CPR];  // single-buffer 32-row tile (8KB / 4KB)

    const int lane = threadIdx.x;
    const int l31  = lane & 31;
    const int hi   = lane >> 5;          // which K-half of the fragment
    const int xr   = l31 & 7;            // read-side swizzle key
    const int base = blockIdx.x * 32;
    const int g    = min(base + l31, npts - 1);   // lane's output row

    // staging lane roles: lane covers chunk t of rows (it*RPI + sub)
    const int sub = lane >> ((CPR == 16) ? 4 : 3);
    const int t   = lane & (CPR - 1);

    const uint16_t* sm = (const uint16_t*)sm4;

    f32x16 acc0 = {0,0,0,0,0,0,0,0,0,0,0,0,0,0,0,0};
    f32x16 acc1 = {0,0,0,0,0,0,0,0,0,0,0,0,0,0,0,0};

    uint4 st0, st1, st2, st3, st4, st5, st6, st7;
    (void)st4; (void)st5; (void)st6; (void)st7;   // unused when NSTG == 4

    auto compute = [&](int k) {
        const uint16_t* bp = wf + (size_t)k * (S * 1024) + lane * 8;
        #pragma unroll
        for (int s = 0; s < S; ++s) {
            const int sl = (2 * s + hi) ^ xr;      // swizzled chunk slot
            bf16x8 a0 = ldb8(sm + (size_t)l31 * CIN + sl * 8);
            bf16x8 b0 = ldb8(bp + s * 1024);
            bf16x8 b1 = ldb8(bp + s * 1024 + 512);
            acc0 = __builtin_amdgcn_mfma_f32_32x32x16_bf16(a0, b0, acc0, 0, 0, 0);
            acc1 = __builtin_amdgcn_mfma_f32_32x32x16_bf16(a0, b1, acc1, 0, 0, 0);
        }
    };

    // prologue: gather tap 0; idxn = index for tap 1 (K >= 2 always here)
    int idxv = nbr[g];
    GATH_ALL();
    int idxn = nbr[(size_t)npts + g];

    // main loop computes taps 0..K-2; gather of tap kk+1 is unconditional
    for (int kk = 0; kk < K - 1; ++kk) {
        LWRT_ALL();                  // tap kk -> LDS (in-order vs prior reads)
        idxv = idxn;
        GATH_ALL();                  // tap kk+1 -> named regs (overlaps MFMAs)
        idxn = nbr[(size_t)min(kk + 2, K - 1) * npts + g];   // clamped
        compute(kk);
    }
    // peeled last tap
    LWRT_ALL();
    compute(K - 1);

    // ---- epilogue: straight from accumulators (validated layout) -----------
    const int c0 = l31, c1 = 32 + l31;
    float sc0 = 0.f, sh0 = 0.f, sc1 = 0.f, sh1 = 0.f;
    if (MODE != 1) {
        sc0 = bnp[c0]; sh0 = bnp[64 + c0];
        sc1 = bnp[c1]; sh1 = bnp[64 + c1];
    }
    #pragma unroll
    for (int reg = 0; reg < 16; ++reg) {
        const int row = (reg & 3) + 8 * (reg >> 2) + 4 * hi;   // 0..31
        const int gr = base + row;
        float v0 = acc0[reg], v1 = acc1[reg];
        if (MODE != 1) {
            v0 = v0 * sc0 + sh0; v0 = v0 >= 0.f ? v0 : 0.01f * v0;
            v1 = v1 * sc1 + sh1; v1 = v1 >= 0.f ? v1 : 0.01f * v1;
        }
        if (gr < npts) {
            if (MODE == 1) { v0 += skip[(size_t)gr * 64 + c0]; v1 += skip[(size_t)gr * 64 + c1]; }
            if (MODE == 2) {
                outf[(size_t)gr * 64 + c0] = v0; outf[(size_t)gr * 64 + c1] = v1;
            } else {
                outb[(size_t)gr * 64 + c0] = f2bf(v0); outb[(size_t)gr * 64 + c1] = f2bf(v1);
            }
        }
    }
}

extern "C" void kernel_launch(void* const* d_in, const int* in_sizes, int n_in,
                              void* d_out, int out_size, void* d_ws, size_t ws_size,
                              hipStream_t stream) {
    const int N = in_sizes[0] / 128;
    const float* x    = (const float*)d_in[0];
    const float* skip = (const float*)d_in[1];
    const float* W1   = (const float*)d_in[2];
    const float* Wt   = (const float*)d_in[3];
    const float* W2   = (const float*)d_in[4];
    const float* W3   = (const float*)d_in[5];
    const float* W4   = (const float*)d_in[6];
    const float* bn   = (const float*)d_in[7];
    const int* nbr1   = (const int*)d_in[8];
    const int* nbrt   = (const int*)d_in[9];
    const int* nbr2   = (const int*)d_in[10];
    const int* nbr3   = (const int*)d_in[11];
    const int* nbr4   = (const int*)d_in[12];

    uint8_t* ws = (uint8_t*)d_ws;
    size_t off = 0;
    auto carve = [&](size_t bytes) -> void* {
        void* p = ws + off;
        off += (bytes + 255) & ~(size_t)255;
        return p;
    };
    uint16_t* xb  = (uint16_t*)carve((size_t)N * 128 * 2);
    uint16_t* hA  = (uint16_t*)carve((size_t)N * 64 * 2);
    uint16_t* hB  = (uint16_t*)carve((size_t)N * 64 * 2);
    uint16_t* p1  = (uint16_t*)carve((size_t)27 * 128 * 64 * 2);
    uint16_t* pt  = (uint16_t*)carve((size_t)27 * 64 * 64 * 2);
    uint16_t* p2  = (uint16_t*)carve((size_t)9 * 64 * 64 * 2);
    uint16_t* p3  = (uint16_t*)carve((size_t)9 * 64 * 64 * 2);
    uint16_t* p4  = (uint16_t*)carve((size_t)27 * 64 * 64 * 2);
    float*    bnp = (float*)carve((size_t)4 * 2 * 64 * 4);

    // prologue: convert + pack (re-done every call; ws is re-poisoned)
    const int n8 = N * 16;  // N*128/8
    convert_x<<<(n8 + 255) / 256, 256, 0, stream>>>(x, xb, n8);
    pack_weights<<<dim3(108, 6), 256, 0, stream>>>(W1, Wt, W2, W3, W4, bn,
                                                   p1, pt, p2, p3, p4, bnp);

    const int grid = (N + 31) / 32;   // 32 rows per 1-wave workgroup
    conv_layer<128, 27, 0><<<grid, 64, 0, stream>>>(xb, p1, nbr1, N, bnp + 0,   nullptr, hA, nullptr);
    conv_layer<64,  27, 1><<<grid, 64, 0, stream>>>(hA, pt, nbrt, N, nullptr,   skip,    hB, nullptr);
    conv_layer<64,   9, 0><<<grid, 64, 0, stream>>>(hB, p2, nbr2, N, bnp + 128, nullptr, hA, nullptr);
    conv_layer<64,   9, 0><<<grid, 64, 0, stream>>>(hA, p3, nbr3, N, bnp + 256, nullptr, hB, nullptr);
    conv_layer<64,  27, 2><<<grid, 64, 0, stream>>>(hB, p4, nbr4, N, bnp + 384, nullptr, nullptr, (float*)d_out);
}